// Round 5
// baseline (29.377 us; speedup 1.0000x reference)
//
#include <hip/hip_runtime.h>

typedef __fp16 h2 __attribute__((ext_vector_type(2)));

#define Hh 64
#define Ww 64

__device__ __forceinline__ h2 f2h2(float f) { return __builtin_bit_cast(h2, f); }

// Wave = one 2-row x 64-col output strip of one (b,c) plane. Lane = column.
// LDS spline table PAIR-ROWS: Pl[i][g][n] = (Wrow[g][n], Wrow[g+1][n]) f16,
// Wrow[r] = spline coef (r-3) scaled; rows 0..2 and 11..13 zero.
// Bank swizzle: dword index n ^= (g & 4) so pair-rows m and m+4 don't alias.
// Tap = 4 ds_read_b128 (pair-rows m, m+2) + 16 fdot2.
// Base path: f32 FMA against SGPR-resident bw (uniform loads, no VGPR cost).
__global__ __launch_bounds__(256, 6) void kan_conv_kernel(
    const float* __restrict__ x,     // (256, 64, 64)
    const float* __restrict__ bw,    // (8, 9)
    const float* __restrict__ sw,    // (8, 9, 8)
    const float* __restrict__ ss,    // (8, 9)
    float* __restrict__ out)         // (256, 8, 64, 64)
{
    __shared__ __align__(16) h2 Pl[9][14][8];

    const int tid = threadIdx.x;
    for (int idx = tid; idx < 9 * 14 * 8; idx += 256) {
        int i   = idx / 112;
        int rem = idx - i * 112;
        int g   = rem >> 3;
        int n   = rem & 7;
        const float sc = ss[n * 9 + i];
        float w0 = 0.f, w1 = 0.f;
        if (g >= 3 && g <= 10)         w0 = sw[(n * 9 + i) * 8 + (g - 3)] * sc;
        if (g + 1 >= 3 && g + 1 <= 10) w1 = sw[(n * 9 + i) * 8 + (g - 2)] * sc;
        h2 p; p.x = (__fp16)w0; p.y = (__fp16)w1;
        Pl[i][g][n ^ (g & 4)] = p;   // bank swizzle
    }
    __syncthreads();

    const int lane = tid & 63;
    const int wv   = tid >> 6;            // wave in block: 0..3
    const int bc   = blockIdx.x >> 3;     // 0..255
    const int grp  = blockIdx.x & 7;      // 0..7
    const int r0   = grp * 8 + wv * 2;    // strip start output row

    const float* __restrict__ xin = x + (size_t)bc * (Hh * Ww);
    float* __restrict__ op = out + (size_t)bc * (8 * Hh * Ww) + (size_t)r0 * Ww + lane;

    // rolling feature sets: [set][col]  col: 0=left,1=center,2=right
    float Fs[3][3];      // silu value (f32)
    h2    Fw01[3][3];    // packed (wr0, wr1)
    h2    Fw23[3][3];    // packed (wr2, wr3)
    int   Fm[3][3];      // span index m (clamped to [0,10])

    auto loadrow = [&](int y, int set) {
        float vC = 0.f, vL = 0.f, vR = 0.f;
        if ((unsigned)y < (unsigned)Hh) {
            const float* row = xin + y * Ww;
            vC = row[lane];
            vL = (lane == 0)  ? 0.f : row[lane - 1];
            vR = (lane == 63) ? 0.f : row[lane + 1];
        }
        float vv[3] = {vL, vC, vR};
        #pragma unroll
        for (int c = 0; c < 3; ++c) {
            float v = vv[c];
            float s = __fdividef(v, 1.f + __expf(-v));          // silu
            float u  = (v + 2.2f) * 2.5f;
            float mf = floorf(u);
            float t  = u - mf;
            int   m  = (int)mf;
            bool  inr = (m >= 0) && (m <= 10);
            m = min(max(m, 0), 10);
            float t2 = t * t, t3 = t2 * t, omt = 1.f - t;
            const float c6 = 1.f / 6.f;
            float w0 = c6 * omt * omt * omt;
            float w1 = c6 * (3.f * t3 - 6.f * t2 + 4.f);
            float w2 = c6 * (-3.f * t3 + 3.f * t2 + 3.f * t + 1.f);
            float w3 = c6 * t3;
            if (!inr) { w0 = 0.f; w1 = 0.f; w2 = 0.f; w3 = 0.f; }
            Fs[set][c]   = s;
            Fw01[set][c] = __builtin_amdgcn_cvt_pkrtz(w0, w1);
            Fw23[set][c] = __builtin_amdgcn_cvt_pkrtz(w2, w3);
            Fm[set][c]   = m;
        }
    };

    loadrow(r0 - 1, 0);
    loadrow(r0,     1);
    loadrow(r0 + 1, 2);

    const float* __restrict__ Pf = (const float*)Pl;

    #pragma unroll
    for (int rr = 0; rr < 2; ++rr) {
        if (rr) loadrow(r0 + 2, 0);

        float acc[8];
        #pragma unroll
        for (int n = 0; n < 8; ++n) acc[n] = 0.f;

        // ---- spline path: 9 taps, 4 ds_read_b128 + 16 fdot2 each ----
        #pragma unroll
        for (int ir = 0; ir < 3; ++ir) {
            const int set = (rr + ir) % 3;
            #pragma unroll
            for (int c = 0; c < 3; ++c) {
                const int i  = ir * 3 + c;
                const int m  = Fm[set][c];
                const int m2 = m + 2;
                const int d1 = (i * 14 + m)  * 8;
                const int d2 = (i * 14 + m2) * 8;
                const int s1 = m  & 4;
                const int s2 = m2 & 4;
                float4 q0 = *(const float4*)(Pf + d1 + s1);        // row-pair m,   n0..3
                float4 q1 = *(const float4*)(Pf + d1 + (s1 ^ 4));  // row-pair m,   n4..7
                float4 q2 = *(const float4*)(Pf + d2 + s2);        // row-pair m+2, n0..3
                float4 q3 = *(const float4*)(Pf + d2 + (s2 ^ 4));  // row-pair m+2, n4..7
                float qa[8] = {q0.x, q0.y, q0.z, q0.w, q1.x, q1.y, q1.z, q1.w};
                float qb[8] = {q2.x, q2.y, q2.z, q2.w, q3.x, q3.y, q3.z, q3.w};
                const h2 w01 = Fw01[set][c];
                const h2 w23 = Fw23[set][c];
                #pragma unroll
                for (int n = 0; n < 8; ++n) {
                    acc[n] = __builtin_amdgcn_fdot2(w01, f2h2(qa[n]), acc[n], false);
                    acc[n] = __builtin_amdgcn_fdot2(w23, f2h2(qb[n]), acc[n], false);
                }
            }
        }

        // ---- base path: f32 FMA with SGPR-resident base weights ----
        #pragma unroll
        for (int ir = 0; ir < 3; ++ir) {
            const int set = (rr + ir) % 3;
            #pragma unroll
            for (int c = 0; c < 3; ++c) {
                const int i = ir * 3 + c;
                const float s = Fs[set][c];
                #pragma unroll
                for (int n = 0; n < 8; ++n)
                    acc[n] += s * bw[n * 9 + i];
            }
        }

        #pragma unroll
        for (int n = 0; n < 8; ++n)
            op[n * (Hh * Ww) + rr * Ww] = acc[n];
    }
}

extern "C" void kernel_launch(void* const* d_in, const int* in_sizes, int n_in,
                              void* d_out, int out_size, void* d_ws, size_t ws_size,
                              hipStream_t stream) {
    const float* x  = (const float*)d_in[0];
    const float* bw = (const float*)d_in[1];
    const float* sw = (const float*)d_in[2];
    const float* ss = (const float*)d_in[3];
    float* out = (float*)d_out;

    dim3 block(256, 1, 1);
    dim3 grid(2048, 1, 1);   // 256 bc * 8 strip-groups; wave = 2-row strip
    hipLaunchKernelGGL(kan_conv_kernel, grid, block, 0, stream, x, bw, sw, ss, out);
}

// Round 6
// 25.821 us; speedup vs baseline: 1.1377x; 1.1377x over previous
//
#include <hip/hip_runtime.h>

typedef __fp16 h2 __attribute__((ext_vector_type(2)));

#define Hh 64
#define Ww 64

__device__ __forceinline__ h2 f2h2(float f) { return __builtin_bit_cast(h2, f); }

// Wave = one 4-row x 64-col output strip of one (b,c) plane. Lane = column.
// LDS spline table PAIR-ROWS: Pl[i][g][n] = (Wrow[g][n], Wrow[g+1][n]) f16,
// Wrow[r] = spline coef (r-3) scaled; rows 0..2 and 11..13 zero.
// XOR bank swizzle (n ^= g&4): line-group map for the gather becomes
// {6,1,3,5,7,0} over m=3..8 (was even-groups-only with m/m+4 aliasing).
// Tap = 4 ds_read_b128 (pair-rows m, m+2) + 16 fdot2.
__global__ __launch_bounds__(256, 4) void kan_conv_kernel(
    const float* __restrict__ x,     // (256, 64, 64)
    const float* __restrict__ bw,    // (8, 9)
    const float* __restrict__ sw,    // (8, 9, 8)
    const float* __restrict__ ss,    // (8, 9)
    float* __restrict__ out)         // (256, 8, 64, 64)
{
    __shared__ __align__(16) h2 Pl[9][14][8];

    const int tid = threadIdx.x;
    for (int idx = tid; idx < 9 * 14 * 8; idx += 256) {
        int i   = idx / 112;
        int rem = idx - i * 112;
        int g   = rem >> 3;
        int n   = rem & 7;
        const float sc = ss[n * 9 + i];
        float w0 = 0.f, w1 = 0.f;
        if (g >= 3 && g <= 10)         w0 = sw[(n * 9 + i) * 8 + (g - 3)] * sc;
        if (g + 1 >= 3 && g + 1 <= 10) w1 = sw[(n * 9 + i) * 8 + (g - 2)] * sc;
        h2 p; p.x = (__fp16)w0; p.y = (__fp16)w1;
        Pl[i][g][n ^ (g & 4)] = p;   // bank swizzle
    }
    __syncthreads();

    const int lane = tid & 63;
    const int wv   = tid >> 6;            // wave in block: 0..3
    const int bc   = blockIdx.x >> 2;     // 0..255
    const int grp  = blockIdx.x & 3;      // 0..3
    const int r0   = grp * 16 + wv * 4;   // strip start output row

    const float* __restrict__ xin = x + (size_t)bc * (Hh * Ww);
    float* __restrict__ op = out + (size_t)bc * (8 * Hh * Ww) + (size_t)r0 * Ww + lane;

    // Base weights hoisted: pairs (i=2p, 2p+1) as f16x2, plus single i=8 (f32).
    h2    hbp[4][8];
    float hb8[8];
    #pragma unroll
    for (int n = 0; n < 8; ++n) {
        #pragma unroll
        for (int p = 0; p < 4; ++p) {
            h2 h;
            h.x = (__fp16)bw[n * 9 + 2 * p];
            h.y = (__fp16)bw[n * 9 + 2 * p + 1];
            hbp[p][n] = h;
        }
        hb8[n] = bw[n * 9 + 8];
    }

    // rolling feature sets: [set][col]  col: 0=left,1=center,2=right
    float Fs[3][3];      // silu value (f32)
    h2    Fw01[3][3];    // packed (wr0, wr1)
    h2    Fw23[3][3];    // packed (wr2, wr3)
    int   Fm[3][3];      // span index m (clamped to [0,10])

    auto loadrow = [&](int y, int set) {
        float vC = 0.f, vL = 0.f, vR = 0.f;
        if ((unsigned)y < (unsigned)Hh) {
            const float* row = xin + y * Ww;
            vC = row[lane];
            vL = (lane == 0)  ? 0.f : row[lane - 1];
            vR = (lane == 63) ? 0.f : row[lane + 1];
        }
        float vv[3] = {vL, vC, vR};
        #pragma unroll
        for (int c = 0; c < 3; ++c) {
            float v = vv[c];
            float s = __fdividef(v, 1.f + __expf(-v));          // silu
            float u  = (v + 2.2f) * 2.5f;
            float mf = floorf(u);
            float t  = u - mf;
            int   m  = (int)mf;
            bool  inr = (m >= 0) && (m <= 10);
            m = min(max(m, 0), 10);
            float t2 = t * t, t3 = t2 * t, omt = 1.f - t;
            const float c6 = 1.f / 6.f;
            float w0 = c6 * omt * omt * omt;
            float w1 = c6 * (3.f * t3 - 6.f * t2 + 4.f);
            float w2 = c6 * (-3.f * t3 + 3.f * t2 + 3.f * t + 1.f);
            float w3 = c6 * t3;
            if (!inr) { w0 = 0.f; w1 = 0.f; w2 = 0.f; w3 = 0.f; }
            Fs[set][c]   = s;
            Fw01[set][c] = __builtin_amdgcn_cvt_pkrtz(w0, w1);
            Fw23[set][c] = __builtin_amdgcn_cvt_pkrtz(w2, w3);
            Fm[set][c]   = m;
        }
    };

    loadrow(r0 - 1, 0);
    loadrow(r0,     1);

    const float* __restrict__ Pf = (const float*)Pl;

    #pragma unroll
    for (int rr = 0; rr < 4; ++rr) {
        loadrow(r0 + rr + 1, (rr + 2) % 3);

        float acc[8];
        #pragma unroll
        for (int n = 0; n < 8; ++n) acc[n] = 0.f;

        // ---- spline path: 9 taps, 4 ds_read_b128 + 16 fdot2 each ----
        #pragma unroll
        for (int ir = 0; ir < 3; ++ir) {
            const int set = (rr + ir) % 3;
            #pragma unroll
            for (int c = 0; c < 3; ++c) {
                const int i  = ir * 3 + c;
                const int m  = Fm[set][c];
                const int m2 = m + 2;
                const int d1 = (i * 14 + m)  * 8;
                const int d2 = (i * 14 + m2) * 8;
                const int s1 = m  & 4;
                const int s2 = m2 & 4;
                float4 q0 = *(const float4*)(Pf + d1 + s1);        // pair m,   n0..3
                float4 q1 = *(const float4*)(Pf + d1 + (s1 ^ 4));  // pair m,   n4..7
                float4 q2 = *(const float4*)(Pf + d2 + s2);        // pair m+2, n0..3
                float4 q3 = *(const float4*)(Pf + d2 + (s2 ^ 4));  // pair m+2, n4..7
                float qa[8] = {q0.x, q0.y, q0.z, q0.w, q1.x, q1.y, q1.z, q1.w};
                float qb[8] = {q2.x, q2.y, q2.z, q2.w, q3.x, q3.y, q3.z, q3.w};
                const h2 w01 = Fw01[set][c];
                const h2 w23 = Fw23[set][c];
                #pragma unroll
                for (int n = 0; n < 8; ++n) {
                    acc[n] = __builtin_amdgcn_fdot2(w01, f2h2(qa[n]), acc[n], false);
                    acc[n] = __builtin_amdgcn_fdot2(w23, f2h2(qb[n]), acc[n], false);
                }
            }
        }

        // ---- base path: silu pairs via fdot2 against hoisted weights ----
        {
            float s9[9];
            #pragma unroll
            for (int i = 0; i < 9; ++i) s9[i] = Fs[(rr + i / 3) % 3][i % 3];
            #pragma unroll
            for (int p = 0; p < 4; ++p) {
                h2 sp = __builtin_amdgcn_cvt_pkrtz(s9[2 * p], s9[2 * p + 1]);
                #pragma unroll
                for (int n = 0; n < 8; ++n)
                    acc[n] = __builtin_amdgcn_fdot2(sp, hbp[p][n], acc[n], false);
            }
            #pragma unroll
            for (int n = 0; n < 8; ++n)
                acc[n] += s9[8] * hb8[n];
        }

        #pragma unroll
        for (int n = 0; n < 8; ++n)
            op[n * (Hh * Ww) + rr * Ww] = acc[n];
    }
}

extern "C" void kernel_launch(void* const* d_in, const int* in_sizes, int n_in,
                              void* d_out, int out_size, void* d_ws, size_t ws_size,
                              hipStream_t stream) {
    const float* x  = (const float*)d_in[0];
    const float* bw = (const float*)d_in[1];
    const float* sw = (const float*)d_in[2];
    const float* ss = (const float*)d_in[3];
    float* out = (float*)d_out;

    dim3 block(256, 1, 1);
    dim3 grid(1024, 1, 1);   // 256 bc * 4 strip-groups; wave = 4-row strip
    hipLaunchKernelGGL(kan_conv_kernel, grid, block, 0, stream, x, bw, sw, ss, out);
}